// Round 7
// baseline (807.820 us; speedup 1.0000x reference)
//
#include <hip/hip_runtime.h>
#include <hip/hip_bf16.h>

#define TSEQ 1024
#define NB   128
#define HID  128
#define QDIM 16

typedef unsigned int  u32;
typedef float f32x2 __attribute__((ext_vector_type(2)));

// ---------------- cross-lane helpers (wave64) ----------------

template<int CTRL>
__device__ __forceinline__ int dpp_i(int x) {
  return __builtin_amdgcn_update_dpp(0, x, CTRL, 0xF, 0xF, true);
}
template<int CTRL>
__device__ __forceinline__ float dpp_f(float x) {
  return __int_as_float(dpp_i<CTRL>(__float_as_int(x)));
}

#ifdef __has_builtin
#if __has_builtin(__builtin_amdgcn_permlane16_swap) && __has_builtin(__builtin_amdgcn_permlane32_swap)
#define HAS_PLS 1
#endif
#endif
#ifndef HAS_PLS
#define HAS_PLS 0
#endif

__device__ __forceinline__ float pls16_sum(float x) {
#if HAS_PLS
  auto r = __builtin_amdgcn_permlane16_swap(__float_as_uint(x), __float_as_uint(x), false, false);
  return __uint_as_float(r[0]) + __uint_as_float(r[1]);
#else
  return x + __shfl_xor(x, 16, 64);
#endif
}
__device__ __forceinline__ float pls32_sum(float x) {
#if HAS_PLS
  auto r = __builtin_amdgcn_permlane32_swap(__float_as_uint(x), __float_as_uint(x), false, false);
  return __uint_as_float(r[0]) + __uint_as_float(r[1]);
#else
  return x + __shfl_xor(x, 32, 64);
#endif
}

#if HAS_PLS
// returns both results of v_permlane32_swap(a, b)
__device__ __forceinline__ void pls32_pair(float a, float b, float& r0, float& r1) {
  auto r = __builtin_amdgcn_permlane32_swap(__float_as_uint(a), __float_as_uint(b), false, false);
  r0 = __uint_as_float(r[0]); r1 = __uint_as_float(r[1]);
}
#endif

__device__ __forceinline__ float rcpf(float x) { return __builtin_amdgcn_rcpf(x); }

__device__ __forceinline__ float ex2(float x) {
#if defined(__has_builtin)
#if __has_builtin(__builtin_amdgcn_exp2f)
  return __builtin_amdgcn_exp2f(x);
#else
  return exp2f(x);
#endif
#else
  return exp2f(x);
#endif
}

__device__ __forceinline__ f32x2 s2(float x) { f32x2 r; r.x = x; r.y = x; return r; }

// CNOT-ladder index map g (verified in R1-R6).
__device__ __forceinline__ int gperm(int t) {
  int u = t;
#define APPLY(c, tt) u ^= (((u >> (3 - (c))) & 1) << (3 - (tt)));
  APPLY(3, 1) APPLY(2, 0) APPLY(1, 3) APPLY(0, 2)
  APPLY(3, 0) APPLY(2, 3) APPLY(1, 2) APPLY(0, 1)
#undef APPLY
  return u;
}

// ---------------- kernel 1: xwP[b,t,j] = x[b,t,:] @ W_x[:,g(j)] + b_in[g(j)] ----------------

__global__ __launch_bounds__(256) void xw_kernel(
    const float* __restrict__ x, const float* __restrict__ W_in,
    const float* __restrict__ b_in, float* __restrict__ xw) {
  __shared__ __align__(16) float xs[16][132];
  __shared__ float wl[2048];
  __shared__ float bl[16];
  const int tid = threadIdx.x;
  const long r0 = (long)blockIdx.x * 16;
#pragma unroll
  for (int i = 0; i < 8; ++i) {
    int idx = tid + i * 256;
    xs[idx >> 7][idx & 127] = x[(r0 + (idx >> 7)) * 128 + (idx & 127)];
  }
#pragma unroll
  for (int i = 0; i < 8; ++i) {
    int idx = tid + i * 256;
    wl[idx] = W_in[2048 + idx];   // W_x = W_in[128:256, :]
  }
  if (tid < 16) bl[tid] = b_in[tid];
  __syncthreads();
  const int rr = tid >> 4, j = tid & 15;
  const int gj = gperm(j);
  float s = bl[gj];
#pragma unroll
  for (int k4 = 0; k4 < 32; ++k4) {
    float4 v = *reinterpret_cast<const float4*>(&xs[rr][k4 * 4]);
    int kb = k4 * 4;
    s = fmaf(v.x, wl[(kb + 0) * 16 + gj], s);
    s = fmaf(v.y, wl[(kb + 1) * 16 + gj], s);
    s = fmaf(v.z, wl[(kb + 2) * 16 + gj], s);
    s = fmaf(v.w, wl[(kb + 3) * 16 + gj], s);
  }
  xw[(r0 + rr) * 16 + j] = s;
}

// ---------------- kernel 2: recurrence. 256 blocks x 1 wave; all-register ----------------
// Both directions atomicAdd 0.5*h onto zeroed out (exactly 2 addends per slot,
// order-independent -> deterministic). No combine kernel, no bwd workspace.

__global__ __launch_bounds__(64)
__attribute__((amdgpu_waves_per_eu(1, 2)))
void qbigru_main(
    const float* __restrict__ W_in,
    const float* __restrict__ W_out,
    const float* __restrict__ b_out,
    const float* __restrict__ thr_f, const float* __restrict__ thr1_f, const float* __restrict__ thu_f,
    const float* __restrict__ thr_b, const float* __restrict__ thr1_b, const float* __restrict__ thu_b,
    const float* __restrict__ xw,
    float* __restrict__ out) {
  const int tid = threadIdx.x;
  const int l4  = tid & 15;
  const int dir = blockIdx.x >> 7;
  const int b   = blockIdx.x & 127;
  const bool lt2 = (tid >> 4) < 2;

  // xor4-within-row via row_shl:4 / row_shr:4 + probe-derived select (convention-proof).
  const int pshl = dpp_i<0x104>(tid);
  const int sel4 = (pshl == (tid ^ 4)) ? ~0 : 0;
  auto xor4f = [&](float x) {
    int a = dpp_i<0x104>(__float_as_int(x));
    int c = dpp_i<0x114>(__float_as_int(x));
    return __int_as_float((a & sel4) | (c & ~sel4));
  };

#if HAS_PLS
  // permlane32_swap half-swap convention probe (wave-uniform boolean).
  bool selA;
  {
    auto q = __builtin_amdgcn_permlane32_swap((u32)tid, (u32)(tid + 4096), false, false);
    u32 q0 = q[0];
    selA = (tid < 32) ? (q0 != (u32)tid) : (q0 == (u32)tid);
  }
#endif

  // Select-free reduce-scatter. Input: v[i] = partial of column (i ^ l4).
  // Output: full 64-lane sum for column l4, replicated in every lane.
  auto bfr = [&](const float* v) -> float {
    float w1[8];
#pragma unroll
    for (int j = 0; j < 8; ++j) w1[j] = v[2 * j] + dpp_f<0xB1>(v[2 * j + 1]);   // col bit0 (xor1)
    float w2[4];
#pragma unroll
    for (int j = 0; j < 4; ++j) w2[j] = w1[2 * j] + dpp_f<0x4E>(w1[2 * j + 1]); // col bit1 (xor2)
    float w3[2];
#pragma unroll
    for (int j = 0; j < 2; ++j) w3[j] = w2[j] + dpp_f<0x128>(w2[j + 2]);        // col bit3 (xor8)
    float y0 = w3[0] + xor4f(w3[1]);                                            // col bit2 (xor4)
    return pls32_sum(pls16_sum(y0));
  };

  // +/- butterfly: eb[B](l) = (-1)^{l_B} * sum_s p[s]*(1-2*bit_B(s)); n2 = sum p.
  auto ebf = [&](float p, float& n2, float* eb) {
    float s4 = xor4f(p);
    float P  = p + s4, M2 = p - s4;
    float dP = dpp_f<0x128>(P), dM2 = dpp_f<0x128>(M2);
    float P3 = P + dP, M3 = P - dP; M2 = M2 + dM2;
    float a1 = dpp_f<0x4E>(P3), a2 = dpp_f<0x4E>(M3), a3 = dpp_f<0x4E>(M2);
    float P1 = P3 + a1, M1 = P3 - a1; M3 += a2; M2 += a3;
    float b0_ = dpp_f<0xB1>(P1), b1_ = dpp_f<0xB1>(M1), b3_ = dpp_f<0xB1>(M3), b2_ = dpp_f<0xB1>(M2);
    n2 = P1 + b0_;
    eb[0] = P1 - b0_; eb[1] = M1 + b1_; eb[3] = M3 + b3_; eb[2] = M2 + b2_;
  };

  // ---- per-lane constants ----
  const float* thr  = dir ? thr_b  : thr_f;
  const float* thr1 = dir ? thr1_b : thr1_f;
  const float* thu  = dir ? thu_b  : thu_f;
  const float* thA  = lt2 ? thr : thu;   // rows 0,1 -> reset VQC; rows 2,3 -> update VQC
  float ch1[4], sh1[4], ch2[4], sh2[4];
#pragma unroll
  for (int i = 0; i < 4; ++i) {
    float a = 0.5f * thA[i];   ch1[i] = cosf(a);  sh1[i] = sinf(a);
    float a2 = 0.5f * thr1[i]; ch2[i] = cosf(a2); sh2[i] = sinf(a2);
  }
  // packed RX-stage constants: chv = (ch,ch), shv = (sh,-sh); stage0 c_s0 = (ch[1], -sh[1])
  f32x2 c1s0;  c1s0.x = ch1[1]; c1s0.y = -sh1[1];
  f32x2 c2s0;  c2s0.x = ch2[1]; c2s0.y = -sh2[1];
  f32x2 chv1_0 = s2(ch1[0]), chv1_1 = s2(ch1[2]), chv1_2 = s2(ch1[3]);
  f32x2 chv2_0 = s2(ch2[0]), chv2_1 = s2(ch2[2]), chv2_2 = s2(ch2[3]);
  f32x2 shv1_0, shv1_1, shv1_2, shv2_0, shv2_1, shv2_2;
  shv1_0.x = sh1[0]; shv1_0.y = -sh1[0];
  shv1_1.x = sh1[2]; shv1_1.y = -sh1[2];
  shv1_2.x = sh1[3]; shv1_2.y = -sh1[3];
  shv2_0.x = sh2[0]; shv2_0.y = -sh2[0];
  shv2_1.x = sh2[2]; shv2_1.y = -sh2[2];
  shv2_2.x = sh2[3]; shv2_2.y = -sh2[3];

  // W_h, XOR layout + CNOT perm folded: slot i holds column g(i ^ l4). Lane covers k = tid, tid+64.
  f32x2 w0p[8], w1p[8];
#pragma unroll
  for (int i = 0; i < 8; ++i) {
    int ja = gperm((2 * i) ^ l4), jb = gperm((2 * i + 1) ^ l4);
    f32x2 a, c;
    a.x = W_in[tid * QDIM + ja];        a.y = W_in[tid * QDIM + jb];
    c.x = W_in[(tid + 64) * QDIM + ja]; c.y = W_in[(tid + 64) * QDIM + jb];
    w0p[i] = a; w1p[i] = c;
  }

  // W_out pk pairs over (m=tid, m=tid+64), wire w = 3-B, e-butterfly sign folded.
  const int ptid = tid ^ 32;
  f32x2 woPpk[4], woPXpk[4];
#pragma unroll
  for (int B = 0; B < 4; ++B) {
    float sgn = ((tid >> B) & 1) ? -1.f : 1.f;
    f32x2 a, c;
    a.x = W_out[(3 - B) * HID + tid] * sgn;
    a.y = W_out[(3 - B) * HID + tid + 64] * sgn;
    c.x = W_out[(3 - B) * HID + ptid] * sgn;
    c.y = W_out[(3 - B) * HID + ptid + 64] * sgn;
    woPpk[B] = a; woPXpk[B] = c;
  }
  const float L2E = 1.4426950408889634f;
  f32x2 nbcpk, bc2pk;
  nbcpk.x = -b_out[tid] * L2E;        nbcpk.y = -b_out[tid + 64] * L2E;
  bc2pk.x =  b_out[tid] * (2.f * L2E); bc2pk.y =  b_out[tid + 64] * (2.f * L2E);

  auto dot4pk = [](const float* e, const f32x2* w) -> f32x2 {
    f32x2 d = s2(e[0]) * w[0];
    d = s2(e[1]) * w[1] + d;
    d = s2(e[2]) * w[2] + d;
    d = s2(e[3]) * w[3] + d;
    return d;
  };

  // packed RX stage: RI=(Re,Im); S=(dpp(Im),dpp(Re)); RI' = chv*RI + shv*S
#define MVSTAGE_PK(CTRL, CHV, SHV) { \
    f32x2 S; S.x = dpp_f<CTRL>(RI.y); S.y = dpp_f<CTRL>(RI.x); \
    RI = (CHV) * RI + (SHV) * S; }

  f32x2 hpk; hpk.x = 0.f; hpk.y = 0.f;   // h[tid], h[tid+64]
  const float* pxw = xw + ((long)b * TSEQ + (dir ? TSEQ - 1 : 0)) * QDIM;
  const long xstep = dir ? -QDIM : QDIM;
  float xc = pxw[l4]; pxw += xstep;
  float xn = pxw[l4]; pxw += xstep;

  float* po = out + (long)b * TSEQ * HID + tid;

#pragma unroll 1
  for (int t = 0; t < TSEQ; ++t) {
    float xnn = pxw[l4]; pxw += xstep;   // prefetch t+2 (ws padded; overrun harmless)

    // ---- y = h @ W_h (permuted cols) + xwP ----
    f32x2 hh0 = s2(hpk.x);
    f32x2 hh1 = s2(hpk.y);
    float v[16];
#pragma unroll
    for (int i = 0; i < 8; ++i) {
      f32x2 a = hh0 * w0p[i] + hh1 * w1p[i];
      v[2 * i] = a.x; v[2 * i + 1] = a.y;
    }
    float yv = bfr(v) + xc;

    // ---- VQC1: packed RX stages; qubit1 (d=4) first with Im=0 ----
    f32x2 RI;
    { f32x2 Y; Y.x = yv; Y.y = xor4f(yv); RI = c1s0 * Y; }
    MVSTAGE_PK(0x128, chv1_0, shv1_0)   // qubit0, d=8
    MVSTAGE_PK(0x4E,  chv1_1, shv1_1)   // qubit2, d=2
    MVSTAGE_PK(0xB1,  chv1_2, shv1_2)   // qubit3, d=1
    float prb = fmaf(RI.x, RI.x, RI.y * RI.y);

    float n2, eb[4];
    ebf(prb, n2, eb);
    float inv = rcpf(n2);   // unitary VQC: n2 == |y|^2, shared by both gate types
    float nic = inv * (-L2E);

    // dots: dO = own gate type / own cols; dXp = own gate type / partner cols.
    f32x2 dO  = dot4pk(eb, woPpk);
    f32x2 dXp = dot4pk(eb, woPXpk);
    f32x2 rd, zd;
#if HAS_PLS
    {
      float u0, u1, w0, w1v;
      { float a0, a1; pls32_pair(dXp.x, dO.x, a0, a1); u0 = a1; }
      { float b0, b1; pls32_pair(dO.x, dXp.x, b0, b1); w0 = b0; }
      { float a0, a1; pls32_pair(dXp.y, dO.y, a0, a1); u1 = a1; }
      { float b0, b1; pls32_pair(dO.y, dXp.y, b0, b1); w1v = b0; }
      rd.x = selA ? u0 : w0;   zd.x = selA ? w0 : u0;
      rd.y = selA ? u1 : w1v;  zd.y = selA ? w1v : u1;
    }
#else
    {
      f32x2 recv;
      recv.x = __shfl_xor(dXp.x, 32, 64);
      recv.y = __shfl_xor(dXp.y, 32, 64);
      rd.x = lt2 ? dO.x : recv.x;  rd.y = lt2 ? dO.y : recv.y;
      zd.x = lt2 ? recv.x : dO.x;  zd.y = lt2 ? recv.y : dO.y;
    }
#endif

    f32x2 ra = rd * s2(nic) + nbcpk;
    f32x2 za = zd * s2(nic) + nbcpk;
    float r0 = rcpf(1.f + ex2(ra.x));
    float r1 = rcpf(1.f + ex2(ra.y));
    float z0 = rcpf(1.f + ex2(za.x));
    float z1 = rcpf(1.f + ex2(za.y));

    // ---- v1 = (r*h) @ W_h + xwP ----
    f32x2 rpk; rpk.x = r0; rpk.y = r1;
    f32x2 rh = rpk * hpk;
    hh0 = s2(rh.x);
    hh1 = s2(rh.y);
#pragma unroll
    for (int i = 0; i < 8; ++i) {
      f32x2 a = hh0 * w0p[i] + hh1 * w1p[i];
      v[2 * i] = a.x; v[2 * i + 1] = a.y;
    }
    float vv = bfr(v) + xc;

    { f32x2 Y; Y.x = vv; Y.y = xor4f(vv); RI = c2s0 * Y; }
    MVSTAGE_PK(0x128, chv2_0, shv2_0)
    MVSTAGE_PK(0x4E,  chv2_1, shv2_1)
    MVSTAGE_PK(0xB1,  chv2_2, shv2_2)
    float prb2 = fmaf(RI.x, RI.x, RI.y * RI.y);

    float n2b, eb2[4];
    ebf(prb2, n2b, eb2);
    float invb = rcpf(n2b);
    f32x2 hd = dot4pk(eb2, woPpk);    // all rows share VQC2 -> own columns only
    f32x2 ha = hd * s2(invb * (2.f * L2E)) + bc2pk;
    float h20 = fmaf(-2.f, rcpf(1.f + ex2(ha.x)), 1.f);
    float h21 = fmaf(-2.f, rcpf(1.f + ex2(ha.y)), 1.f);

    f32x2 h2pk; h2pk.x = h20; h2pk.y = h21;
    f32x2 zpk;  zpk.x  = z0;  zpk.y  = z1;
    hpk = zpk * (h2pk - hpk) + hpk;

    f32x2 opk = hpk * s2(0.5f);
    atomicAdd(po,      opk.x);
    atomicAdd(po + 64, opk.y);
    po += HID;

    xc = xn; xn = xnn;
  }
#undef MVSTAGE_PK
}

// ---------------- launch ----------------

extern "C" void kernel_launch(void* const* d_in, const int* in_sizes, int n_in,
                              void* d_out, int out_size, void* d_ws, size_t ws_size,
                              hipStream_t stream) {
  const float* x     = (const float*)d_in[0];
  const float* W_in  = (const float*)d_in[1];
  const float* b_in  = (const float*)d_in[2];
  const float* W_out = (const float*)d_in[3];
  const float* b_out = (const float*)d_in[4];
  const float* thr_f  = (const float*)d_in[5];
  const float* thr1_f = (const float*)d_in[6];
  const float* thu_f  = (const float*)d_in[7];
  const float* thr_b  = (const float*)d_in[8];
  const float* thr1_b = (const float*)d_in[9];
  const float* thu_b  = (const float*)d_in[10];
  float* out = (float*)d_out;

  char* ws = (char*)d_ws;
  const size_t PAD = 4096;   // xw prefetch over/under-run guard
  float* xw = (float*)(ws + PAD);

  // zero out every launch: both directions accumulate with atomicAdd.
  hipMemsetAsync(d_out, 0, (size_t)out_size * sizeof(float), stream);

  xw_kernel<<<(NB * TSEQ) / 16, 256, 0, stream>>>(x, W_in, b_in, xw);

  qbigru_main<<<256, 64, 0, stream>>>(W_in, W_out, b_out,
      thr_f, thr1_f, thu_f, thr_b, thr1_b, thu_b, xw, out);
}

// Round 8
// 733.239 us; speedup vs baseline: 1.1017x; 1.1017x over previous
//
#include <hip/hip_runtime.h>
#include <hip/hip_bf16.h>

#define TSEQ 1024
#define NB   128
#define HID  128
#define QDIM 16

typedef unsigned int  u32;
typedef unsigned short u16;
typedef float f32x2 __attribute__((ext_vector_type(2)));

// ---------------- cross-lane helpers (wave64) ----------------

template<int CTRL>
__device__ __forceinline__ int dpp_i(int x) {
  return __builtin_amdgcn_update_dpp(0, x, CTRL, 0xF, 0xF, true);
}
template<int CTRL>
__device__ __forceinline__ float dpp_f(float x) {
  return __int_as_float(dpp_i<CTRL>(__float_as_int(x)));
}

#ifdef __has_builtin
#if __has_builtin(__builtin_amdgcn_permlane16_swap) && __has_builtin(__builtin_amdgcn_permlane32_swap)
#define HAS_PLS 1
#endif
#endif
#ifndef HAS_PLS
#define HAS_PLS 0
#endif

__device__ __forceinline__ float pls16_sum(float x) {
#if HAS_PLS
  auto r = __builtin_amdgcn_permlane16_swap(__float_as_uint(x), __float_as_uint(x), false, false);
  return __uint_as_float(r[0]) + __uint_as_float(r[1]);
#else
  return x + __shfl_xor(x, 16, 64);
#endif
}
__device__ __forceinline__ float pls32_sum(float x) {
#if HAS_PLS
  auto r = __builtin_amdgcn_permlane32_swap(__float_as_uint(x), __float_as_uint(x), false, false);
  return __uint_as_float(r[0]) + __uint_as_float(r[1]);
#else
  return x + __shfl_xor(x, 32, 64);
#endif
}
__device__ __forceinline__ float pls32_other(float x) { return pls32_sum(x) - x; }

__device__ __forceinline__ float rcpf(float x) { return __builtin_amdgcn_rcpf(x); }

__device__ __forceinline__ float ex2(float x) {
#if defined(__has_builtin)
#if __has_builtin(__builtin_amdgcn_exp2f)
  return __builtin_amdgcn_exp2f(x);
#else
  return exp2f(x);
#endif
#else
  return exp2f(x);
#endif
}

__device__ __forceinline__ u16 f2bf(float f) {
  u32 u = __float_as_uint(f);
  u32 r = (u + 0x7FFFu + ((u >> 16) & 1u)) >> 16;
  return (u16)r;
}

__device__ __forceinline__ f32x2 s2(float x) { f32x2 r; r.x = x; r.y = x; return r; }

// CNOT-ladder index map g (verified in R1-R7).
__device__ __forceinline__ int gperm(int t) {
  int u = t;
#define APPLY(c, tt) u ^= (((u >> (3 - (c))) & 1) << (3 - (tt)));
  APPLY(3, 1) APPLY(2, 0) APPLY(1, 3) APPLY(0, 2)
  APPLY(3, 0) APPLY(2, 3) APPLY(1, 2) APPLY(0, 1)
#undef APPLY
  return u;
}

// ---------------- kernel 1: xwP[b,t,j] = x[b,t,:] @ W_x[:,g(j)] + b_in[g(j)] ----------------

__global__ __launch_bounds__(256) void xw_kernel(
    const float* __restrict__ x, const float* __restrict__ W_in,
    const float* __restrict__ b_in, float* __restrict__ xw) {
  __shared__ __align__(16) float xs[16][132];
  __shared__ float wl[2048];
  __shared__ float bl[16];
  const int tid = threadIdx.x;
  const long r0 = (long)blockIdx.x * 16;
#pragma unroll
  for (int i = 0; i < 8; ++i) {
    int idx = tid + i * 256;
    xs[idx >> 7][idx & 127] = x[(r0 + (idx >> 7)) * 128 + (idx & 127)];
  }
#pragma unroll
  for (int i = 0; i < 8; ++i) {
    int idx = tid + i * 256;
    wl[idx] = W_in[2048 + idx];   // W_x = W_in[128:256, :]
  }
  if (tid < 16) bl[tid] = b_in[tid];
  __syncthreads();
  const int rr = tid >> 4, j = tid & 15;
  const int gj = gperm(j);
  float s = bl[gj];
#pragma unroll
  for (int k4 = 0; k4 < 32; ++k4) {
    float4 v = *reinterpret_cast<const float4*>(&xs[rr][k4 * 4]);
    int kb = k4 * 4;
    s = fmaf(v.x, wl[(kb + 0) * 16 + gj], s);
    s = fmaf(v.y, wl[(kb + 1) * 16 + gj], s);
    s = fmaf(v.z, wl[(kb + 2) * 16 + gj], s);
    s = fmaf(v.w, wl[(kb + 3) * 16 + gj], s);
  }
  xw[(r0 + rr) * 16 + j] = s;
}

// ---------------- kernel 2: recurrence. 256 blocks x 1 wave; all-register ----------------

template<bool BF16WS>
__global__ __launch_bounds__(64)
__attribute__((amdgpu_waves_per_eu(1, 2)))
void qbigru_main(
    const float* __restrict__ W_in,
    const float* __restrict__ W_out,
    const float* __restrict__ b_out,
    const float* __restrict__ thr_f, const float* __restrict__ thr1_f, const float* __restrict__ thu_f,
    const float* __restrict__ thr_b, const float* __restrict__ thr1_b, const float* __restrict__ thu_b,
    const float* __restrict__ xw,
    float* __restrict__ out,
    void* __restrict__ bwdws) {
  const int tid = threadIdx.x;
  const int l4  = tid & 15;
  const int dir = blockIdx.x >> 7;
  const int b   = blockIdx.x & 127;
  const bool lt2 = (tid >> 4) < 2;

  // xor4-within-row via row_shl:4 / row_shr:4 + probe-derived select (convention-proof).
  const int pshl = dpp_i<0x104>(tid);
  const int sel4 = (pshl == (tid ^ 4)) ? ~0 : 0;
  auto xor4f = [&](float x) {
    int a = dpp_i<0x104>(__float_as_int(x));
    int c = dpp_i<0x114>(__float_as_int(x));
    return __int_as_float((a & sel4) | (c & ~sel4));
  };

  // Select-free reduce-scatter. Input: v[i] = partial of column (i ^ l4).
  // Output: full 64-lane sum for column l4, replicated in every lane.
  auto bfr = [&](const float* v) -> float {
    float w1[8];
#pragma unroll
    for (int j = 0; j < 8; ++j) w1[j] = v[2 * j] + dpp_f<0xB1>(v[2 * j + 1]);   // col bit0 (xor1)
    float w2[4];
#pragma unroll
    for (int j = 0; j < 4; ++j) w2[j] = w1[2 * j] + dpp_f<0x4E>(w1[2 * j + 1]); // col bit1 (xor2)
    float w3[2];
#pragma unroll
    for (int j = 0; j < 2; ++j) w3[j] = w2[j] + dpp_f<0x128>(w2[j + 2]);        // col bit3 (xor8)
    float y0 = w3[0] + xor4f(w3[1]);                                            // col bit2 (xor4)
    return pls32_sum(pls16_sum(y0));
  };

  // +/- butterfly: eb[B](l) = (-1)^{l_B} * sum_s p[s]*(1-2*bit_B(s)); n2 = sum p.
  auto ebf = [&](float p, float& n2, float* eb) {
    float s4 = xor4f(p);
    float P  = p + s4, M2 = p - s4;
    float dP = dpp_f<0x128>(P), dM2 = dpp_f<0x128>(M2);
    float P3 = P + dP, M3 = P - dP; M2 = M2 + dM2;
    float a1 = dpp_f<0x4E>(P3), a2 = dpp_f<0x4E>(M3), a3 = dpp_f<0x4E>(M2);
    float P1 = P3 + a1, M1 = P3 - a1; M3 += a2; M2 += a3;
    float b0_ = dpp_f<0xB1>(P1), b1_ = dpp_f<0xB1>(M1), b3_ = dpp_f<0xB1>(M3), b2_ = dpp_f<0xB1>(M2);
    n2 = P1 + b0_;
    eb[0] = P1 - b0_; eb[1] = M1 + b1_; eb[3] = M3 + b3_; eb[2] = M2 + b2_;
  };

  // ---- per-lane constants ----
  const float* thr  = dir ? thr_b  : thr_f;
  const float* thr1 = dir ? thr1_b : thr1_f;
  const float* thu  = dir ? thu_b  : thu_f;
  const float* thA  = lt2 ? thr : thu;   // rows 0,1 -> reset VQC; rows 2,3 -> update VQC
  float ch1[4], sh1[4], ch2[4], sh2[4];
#pragma unroll
  for (int i = 0; i < 4; ++i) {
    float a = 0.5f * thA[i];   ch1[i] = cosf(a);  sh1[i] = sinf(a);
    float a2 = 0.5f * thr1[i]; ch2[i] = cosf(a2); sh2[i] = sinf(a2);
  }
  // packed RX-stage constants: chv = (ch,ch), shv = (sh,-sh); stage0 c_s0 = (ch[1], -sh[1])
  f32x2 c1s0;  c1s0.x = ch1[1]; c1s0.y = -sh1[1];
  f32x2 c2s0;  c2s0.x = ch2[1]; c2s0.y = -sh2[1];
  f32x2 chv1_0 = s2(ch1[0]), chv1_1 = s2(ch1[2]), chv1_2 = s2(ch1[3]);
  f32x2 chv2_0 = s2(ch2[0]), chv2_1 = s2(ch2[2]), chv2_2 = s2(ch2[3]);
  f32x2 shv1_0, shv1_1, shv1_2, shv2_0, shv2_1, shv2_2;
  shv1_0.x = sh1[0]; shv1_0.y = -sh1[0];
  shv1_1.x = sh1[2]; shv1_1.y = -sh1[2];
  shv1_2.x = sh1[3]; shv1_2.y = -sh1[3];
  shv2_0.x = sh2[0]; shv2_0.y = -sh2[0];
  shv2_1.x = sh2[2]; shv2_1.y = -sh2[2];
  shv2_2.x = sh2[3]; shv2_2.y = -sh2[3];

  // W_h, XOR layout + CNOT perm folded: slot i holds column g(i ^ l4). Lane covers k = tid, tid+64.
  f32x2 w0p[8], w1p[8];
#pragma unroll
  for (int i = 0; i < 8; ++i) {
    int ja = gperm((2 * i) ^ l4), jb = gperm((2 * i + 1) ^ l4);
    f32x2 a, c;
    a.x = W_in[tid * QDIM + ja];        a.y = W_in[tid * QDIM + jb];
    c.x = W_in[(tid + 64) * QDIM + ja]; c.y = W_in[(tid + 64) * QDIM + jb];
    w0p[i] = a; w1p[i] = c;
  }

  // W_out pk pairs over (m=tid, m=tid+64), wire w = 3-B, e-butterfly sign folded.
  const int ptid = tid ^ 32;
  f32x2 woPpk[4], woPXpk[4];
#pragma unroll
  for (int B = 0; B < 4; ++B) {
    float sgn = ((tid >> B) & 1) ? -1.f : 1.f;
    f32x2 a, c;
    a.x = W_out[(3 - B) * HID + tid] * sgn;
    a.y = W_out[(3 - B) * HID + tid + 64] * sgn;
    c.x = W_out[(3 - B) * HID + ptid] * sgn;
    c.y = W_out[(3 - B) * HID + ptid + 64] * sgn;
    woPpk[B] = a; woPXpk[B] = c;
  }
  const float L2E = 1.4426950408889634f;
  f32x2 nbcpk, bc2pk;
  nbcpk.x = -b_out[tid] * L2E;        nbcpk.y = -b_out[tid + 64] * L2E;
  bc2pk.x =  b_out[tid] * (2.f * L2E); bc2pk.y =  b_out[tid + 64] * (2.f * L2E);

  // 2-level tree dot (1 level shorter than serial fma chain)
  auto dot4pk = [](const float* e, const f32x2* w) -> f32x2 {
    f32x2 d01 = s2(e[1]) * w[1] + s2(e[0]) * w[0];
    f32x2 d23 = s2(e[3]) * w[3] + s2(e[2]) * w[2];
    return d01 + d23;
  };

  // packed RX stage: RI=(Re,Im); S=(dpp(Im),dpp(Re)); RI' = chv*RI + shv*S
#define MVSTAGE_PK(CTRL, CHV, SHV) { \
    f32x2 S; S.x = dpp_f<CTRL>(RI.y); S.y = dpp_f<CTRL>(RI.x); \
    RI = (CHV) * RI + (SHV) * S; }

  f32x2 hpk; hpk.x = 0.f; hpk.y = 0.f;   // h[tid], h[tid+64]
  const float* pxw = xw + ((long)b * TSEQ + (dir ? TSEQ - 1 : 0)) * QDIM;
  const long xstep = dir ? -QDIM : QDIM;
  float xc = pxw[l4]; pxw += xstep;
  float xn = pxw[l4]; pxw += xstep;

  float* po  = out + (long)b * TSEQ * HID + tid;
  float* pbf = (float*)bwdws + (long)b * TSEQ * HID + tid;
  u16*   pbh = (u16*)bwdws + (long)b * TSEQ * HID + tid;

#pragma unroll 1
  for (int t = 0; t < TSEQ; ++t) {
    float xnn = pxw[l4]; pxw += xstep;   // prefetch t+2 (ws padded; overrun harmless)

    // ---- y = h @ W_h (permuted cols) + xwP ----
    f32x2 hh0 = s2(hpk.x);
    f32x2 hh1 = s2(hpk.y);
    float v[16];
#pragma unroll
    for (int i = 0; i < 8; ++i) {
      f32x2 a = hh0 * w0p[i] + hh1 * w1p[i];
      v[2 * i] = a.x; v[2 * i + 1] = a.y;
    }
    float yv = bfr(v) + xc;

    // ---- VQC1: packed RX stages; qubit1 (d=4) first with Im=0 ----
    f32x2 RI;
    { f32x2 Y; Y.x = yv; Y.y = xor4f(yv); RI = c1s0 * Y; }
    MVSTAGE_PK(0x128, chv1_0, shv1_0)   // qubit0, d=8
    MVSTAGE_PK(0x4E,  chv1_1, shv1_1)   // qubit2, d=2
    MVSTAGE_PK(0xB1,  chv1_2, shv1_2)   // qubit3, d=1
    float prb = fmaf(RI.x, RI.x, RI.y * RI.y);

    float n2, eb[4];
    ebf(prb, n2, eb);
    float inv = rcpf(n2);   // unitary VQC: n2 == |y|^2, shared by both gate types
    float nic = inv * (-L2E);

    // dots: dO = own gate type / own cols; dXp = own gate type / partner cols;
    // one pls32 crossing delivers the other gate type's dots for our m-pair.
    f32x2 dO  = dot4pk(eb, woPpk);
    f32x2 dXp = dot4pk(eb, woPXpk);
    f32x2 recv;
    recv.x = pls32_other(dXp.x);
    recv.y = pls32_other(dXp.y);
    f32x2 rd, zd;
    rd.x = lt2 ? dO.x : recv.x;  rd.y = lt2 ? dO.y : recv.y;
    zd.x = lt2 ? recv.x : dO.x;  zd.y = lt2 ? recv.y : dO.y;

    f32x2 ra = rd * s2(nic) + nbcpk;
    f32x2 za = zd * s2(nic) + nbcpk;
    float r0 = rcpf(1.f + ex2(ra.x));
    float r1 = rcpf(1.f + ex2(ra.y));
    float z0 = rcpf(1.f + ex2(za.x));
    float z1 = rcpf(1.f + ex2(za.y));

    // ---- v1 = (r*h) @ W_h + xwP ----
    f32x2 rpk; rpk.x = r0; rpk.y = r1;
    f32x2 rh = rpk * hpk;
    hh0 = s2(rh.x);
    hh1 = s2(rh.y);
#pragma unroll
    for (int i = 0; i < 8; ++i) {
      f32x2 a = hh0 * w0p[i] + hh1 * w1p[i];
      v[2 * i] = a.x; v[2 * i + 1] = a.y;
    }
    float vv = bfr(v) + xc;

    { f32x2 Y; Y.x = vv; Y.y = xor4f(vv); RI = c2s0 * Y; }
    MVSTAGE_PK(0x128, chv2_0, shv2_0)
    MVSTAGE_PK(0x4E,  chv2_1, shv2_1)
    MVSTAGE_PK(0xB1,  chv2_2, shv2_2)
    float prb2 = fmaf(RI.x, RI.x, RI.y * RI.y);

    float n2b, eb2[4];
    ebf(prb2, n2b, eb2);
    float invb = rcpf(n2b);
    f32x2 hd = dot4pk(eb2, woPpk);    // all rows share VQC2 -> own columns only
    f32x2 ha = hd * s2(invb * (2.f * L2E)) + bc2pk;
    float h20 = fmaf(-2.f, rcpf(1.f + ex2(ha.x)), 1.f);
    float h21 = fmaf(-2.f, rcpf(1.f + ex2(ha.y)), 1.f);

    f32x2 h2pk; h2pk.x = h20; h2pk.y = h21;
    f32x2 zpk;  zpk.x  = z0;  zpk.y  = z1;
    hpk = zpk * (h2pk - hpk) + hpk;

    f32x2 opk = hpk * s2(0.5f);
    if (dir == 0) {
      po[0]  = opk.x;
      po[64] = opk.y;
      po += HID;
    } else if (BF16WS) {
      pbh[0]  = f2bf(opk.x);
      pbh[64] = f2bf(opk.y);
      pbh += HID;
    } else {
      pbf[0]  = opk.x;
      pbf[64] = opk.y;
      pbf += HID;
    }

    xc = xn; xn = xnn;
  }
#undef MVSTAGE_PK
}

// ---------------- kernel 3: out += bwd trajectory ----------------

template<bool BF16WS>
__global__ __launch_bounds__(256) void combine_k(float* __restrict__ out,
                                                 const void* __restrict__ bwd, long n4) {
  long i = (long)blockIdx.x * 256 + threadIdx.x;
  const long stride = (long)gridDim.x * 256;
  for (; i < n4; i += stride) {
    float4 o = reinterpret_cast<float4*>(out)[i];
    float ax, ay, az, aw;
    if (BF16WS) {
      ushort4 u = reinterpret_cast<const ushort4*>(bwd)[i];
      ax = __uint_as_float((u32)u.x << 16);
      ay = __uint_as_float((u32)u.y << 16);
      az = __uint_as_float((u32)u.z << 16);
      aw = __uint_as_float((u32)u.w << 16);
    } else {
      float4 a = reinterpret_cast<const float4*>(bwd)[i];
      ax = a.x; ay = a.y; az = a.z; aw = a.w;
    }
    o.x += ax; o.y += ay; o.z += az; o.w += aw;
    reinterpret_cast<float4*>(out)[i] = o;
  }
}

// ---------------- launch ----------------

extern "C" void kernel_launch(void* const* d_in, const int* in_sizes, int n_in,
                              void* d_out, int out_size, void* d_ws, size_t ws_size,
                              hipStream_t stream) {
  const float* x     = (const float*)d_in[0];
  const float* W_in  = (const float*)d_in[1];
  const float* b_in  = (const float*)d_in[2];
  const float* W_out = (const float*)d_in[3];
  const float* b_out = (const float*)d_in[4];
  const float* thr_f  = (const float*)d_in[5];
  const float* thr1_f = (const float*)d_in[6];
  const float* thu_f  = (const float*)d_in[7];
  const float* thr_b  = (const float*)d_in[8];
  const float* thr1_b = (const float*)d_in[9];
  const float* thu_b  = (const float*)d_in[10];
  float* out = (float*)d_out;

  char* ws = (char*)d_ws;
  const size_t PAD = 4096;   // xw prefetch over/under-run guard
  const size_t xw_bytes = (size_t)NB * TSEQ * QDIM * sizeof(float);   // 8 MB
  float* xw = (float*)(ws + PAD);
  void* bwd = (void*)(ws + PAD + xw_bytes + PAD);
  const size_t need_f32 = 2 * PAD + xw_bytes + (size_t)NB * TSEQ * HID * sizeof(float);
  const bool f32ws = (ws_size >= need_f32);

  xw_kernel<<<(NB * TSEQ) / 16, 256, 0, stream>>>(x, W_in, b_in, xw);

  if (f32ws) {
    qbigru_main<false><<<256, 64, 0, stream>>>(W_in, W_out, b_out,
        thr_f, thr1_f, thu_f, thr_b, thr1_b, thu_b, xw, out, bwd);
  } else {
    qbigru_main<true><<<256, 64, 0, stream>>>(W_in, W_out, b_out,
        thr_f, thr1_f, thu_f, thr_b, thr1_b, thu_b, xw, out, bwd);
  }

  const long n4 = (long)NB * TSEQ * HID / 4;
  if (f32ws) combine_k<false><<<2048, 256, 0, stream>>>(out, bwd, n4);
  else       combine_k<true><<<2048, 256, 0, stream>>>(out, bwd, n4);
}

// Round 9
// 605.680 us; speedup vs baseline: 1.3337x; 1.2106x over previous
//
#include <hip/hip_runtime.h>
#include <hip/hip_bf16.h>

#define TSEQ 1024
#define NB   128
#define HID  128
#define QDIM 16

typedef unsigned int  u32;
typedef unsigned short u16;
typedef float f32x2 __attribute__((ext_vector_type(2)));

// ---------------- cross-lane helpers (wave64) ----------------

template<int CTRL>
__device__ __forceinline__ int dpp_i(int x) {
  return __builtin_amdgcn_update_dpp(0, x, CTRL, 0xF, 0xF, true);
}
template<int CTRL>
__device__ __forceinline__ float dpp_f(float x) {
  return __int_as_float(dpp_i<CTRL>(__float_as_int(x)));
}

#ifdef __has_builtin
#if __has_builtin(__builtin_amdgcn_permlane16_swap) && __has_builtin(__builtin_amdgcn_permlane32_swap)
#define HAS_PLS 1
#endif
#endif
#ifndef HAS_PLS
#define HAS_PLS 0
#endif

__device__ __forceinline__ float pls16_sum(float x) {
#if HAS_PLS
  auto r = __builtin_amdgcn_permlane16_swap(__float_as_uint(x), __float_as_uint(x), false, false);
  return __uint_as_float(r[0]) + __uint_as_float(r[1]);
#else
  return x + __shfl_xor(x, 16, 64);
#endif
}
__device__ __forceinline__ float pls32_sum(float x) {
#if HAS_PLS
  auto r = __builtin_amdgcn_permlane32_swap(__float_as_uint(x), __float_as_uint(x), false, false);
  return __uint_as_float(r[0]) + __uint_as_float(r[1]);
#else
  return x + __shfl_xor(x, 32, 64);
#endif
}
__device__ __forceinline__ float pls32_other(float x) { return pls32_sum(x) - x; }

__device__ __forceinline__ float rcpf(float x) { return __builtin_amdgcn_rcpf(x); }

__device__ __forceinline__ float ex2(float x) {
#if defined(__has_builtin)
#if __has_builtin(__builtin_amdgcn_exp2f)
  return __builtin_amdgcn_exp2f(x);
#else
  return exp2f(x);
#endif
#else
  return exp2f(x);
#endif
}

__device__ __forceinline__ u16 f2bf(float f) {
  u32 u = __float_as_uint(f);
  u32 r = (u + 0x7FFFu + ((u >> 16) & 1u)) >> 16;
  return (u16)r;
}

__device__ __forceinline__ f32x2 s2(float x) { f32x2 r; r.x = x; r.y = x; return r; }

// CNOT-ladder index map g (verified in R1-R8).
__device__ __forceinline__ int gperm(int t) {
  int u = t;
#define APPLY(c, tt) u ^= (((u >> (3 - (c))) & 1) << (3 - (tt)));
  APPLY(3, 1) APPLY(2, 0) APPLY(1, 3) APPLY(0, 2)
  APPLY(3, 0) APPLY(2, 3) APPLY(1, 2) APPLY(0, 1)
#undef APPLY
  return u;
}

// ---------------- kernel 1: xwP[b,t,j] = x[b,t,:] @ W_x[:,g(j)] + b_in[g(j)] ----------------

__global__ __launch_bounds__(256) void xw_kernel(
    const float* __restrict__ x, const float* __restrict__ W_in,
    const float* __restrict__ b_in, float* __restrict__ xw) {
  __shared__ __align__(16) float xs[16][132];
  __shared__ float wl[2048];
  __shared__ float bl[16];
  const int tid = threadIdx.x;
  const long r0 = (long)blockIdx.x * 16;
#pragma unroll
  for (int i = 0; i < 8; ++i) {
    int idx = tid + i * 256;
    xs[idx >> 7][idx & 127] = x[(r0 + (idx >> 7)) * 128 + (idx & 127)];
  }
#pragma unroll
  for (int i = 0; i < 8; ++i) {
    int idx = tid + i * 256;
    wl[idx] = W_in[2048 + idx];   // W_x = W_in[128:256, :]
  }
  if (tid < 16) bl[tid] = b_in[tid];
  __syncthreads();
  const int rr = tid >> 4, j = tid & 15;
  const int gj = gperm(j);
  float s = bl[gj];
#pragma unroll
  for (int k4 = 0; k4 < 32; ++k4) {
    float4 v = *reinterpret_cast<const float4*>(&xs[rr][k4 * 4]);
    int kb = k4 * 4;
    s = fmaf(v.x, wl[(kb + 0) * 16 + gj], s);
    s = fmaf(v.y, wl[(kb + 1) * 16 + gj], s);
    s = fmaf(v.z, wl[(kb + 2) * 16 + gj], s);
    s = fmaf(v.w, wl[(kb + 3) * 16 + gj], s);
  }
  xw[(r0 + rr) * 16 + j] = s;
}

// ---------------- kernel 2: recurrence. 256 blocks x 1 wave; all-register ----------------
// VQC collapsed analytically: for real psi and one RX layer,
//   RX†(θ) Z RX(θ) = cosθ·Z + sinθ·Y  and  <psi|Y|psi> = 0 for real psi,
// so expval[w] = cosθ_w * Σ_s z_w(s)·yP[s]² / |y|². The cosθ_w factors are
// folded into the W_out constant tables (woPpk/woPXpk: own-VQC thetas;
// woHpk: VQC2 thetas). The e-butterfly input is just yv².

template<bool BF16WS>
__global__ __launch_bounds__(64)
__attribute__((amdgpu_waves_per_eu(1, 2)))
void qbigru_main(
    const float* __restrict__ W_in,
    const float* __restrict__ W_out,
    const float* __restrict__ b_out,
    const float* __restrict__ thr_f, const float* __restrict__ thr1_f, const float* __restrict__ thu_f,
    const float* __restrict__ thr_b, const float* __restrict__ thr1_b, const float* __restrict__ thu_b,
    const float* __restrict__ xw,
    float* __restrict__ out,
    void* __restrict__ bwdws) {
  const int tid = threadIdx.x;
  const int l4  = tid & 15;
  const int dir = blockIdx.x >> 7;
  const int b   = blockIdx.x & 127;
  const bool lt2 = (tid >> 4) < 2;

  // xor4-within-row via row_shl:4 / row_shr:4 + probe-derived select (convention-proof).
  const int pshl = dpp_i<0x104>(tid);
  const int sel4 = (pshl == (tid ^ 4)) ? ~0 : 0;
  auto xor4f = [&](float x) {
    int a = dpp_i<0x104>(__float_as_int(x));
    int c = dpp_i<0x114>(__float_as_int(x));
    return __int_as_float((a & sel4) | (c & ~sel4));
  };

  // Select-free reduce-scatter. Input: v[i] = partial of column (i ^ l4).
  // Output: full 64-lane sum for column l4, replicated in every lane.
  auto bfr = [&](const float* v) -> float {
    float w1[8];
#pragma unroll
    for (int j = 0; j < 8; ++j) w1[j] = v[2 * j] + dpp_f<0xB1>(v[2 * j + 1]);   // col bit0 (xor1)
    float w2[4];
#pragma unroll
    for (int j = 0; j < 4; ++j) w2[j] = w1[2 * j] + dpp_f<0x4E>(w1[2 * j + 1]); // col bit1 (xor2)
    float w3[2];
#pragma unroll
    for (int j = 0; j < 2; ++j) w3[j] = w2[j] + dpp_f<0x128>(w2[j + 2]);        // col bit3 (xor8)
    float y0 = w3[0] + xor4f(w3[1]);                                            // col bit2 (xor4)
    return pls32_sum(pls16_sum(y0));
  };

  // +/- butterfly: eb[B](l) = (-1)^{l_B} * sum_s p[s]*(1-2*bit_B(s)); n2 = sum p.
  auto ebf = [&](float p, float& n2, float* eb) {
    float s4 = xor4f(p);
    float P  = p + s4, M2 = p - s4;
    float dP = dpp_f<0x128>(P), dM2 = dpp_f<0x128>(M2);
    float P3 = P + dP, M3 = P - dP; M2 = M2 + dM2;
    float a1 = dpp_f<0x4E>(P3), a2 = dpp_f<0x4E>(M3), a3 = dpp_f<0x4E>(M2);
    float P1 = P3 + a1, M1 = P3 - a1; M3 += a2; M2 += a3;
    float b0_ = dpp_f<0xB1>(P1), b1_ = dpp_f<0xB1>(M1), b3_ = dpp_f<0xB1>(M3), b2_ = dpp_f<0xB1>(M2);
    n2 = P1 + b0_;
    eb[0] = P1 - b0_; eb[1] = M1 + b1_; eb[3] = M3 + b3_; eb[2] = M2 + b2_;
  };

  // ---- per-lane constants ----
  const float* thr  = dir ? thr_b  : thr_f;
  const float* thr1 = dir ? thr1_b : thr1_f;
  const float* thu  = dir ? thu_b  : thu_f;
  const float* thA  = lt2 ? thr : thu;   // rows 0,1 -> reset VQC; rows 2,3 -> update VQC

  // W_h, XOR layout + CNOT perm folded: slot i holds column g(i ^ l4). Lane covers k = tid, tid+64.
  f32x2 w0p[8], w1p[8];
#pragma unroll
  for (int i = 0; i < 8; ++i) {
    int ja = gperm((2 * i) ^ l4), jb = gperm((2 * i + 1) ^ l4);
    f32x2 a, c;
    a.x = W_in[tid * QDIM + ja];        a.y = W_in[tid * QDIM + jb];
    c.x = W_in[(tid + 64) * QDIM + ja]; c.y = W_in[(tid + 64) * QDIM + jb];
    w0p[i] = a; w1p[i] = c;
  }

  // W_out pk pairs over (m=tid, m=tid+64), wire w = 3-B, with e-butterfly sign
  // (-1)^{l_B} AND the analytic cos(theta_w) VQC factor folded in.
  // woPpk/woPXpk: own-VQC1 theta (thA); woHpk: VQC2 theta (thr1).
  const int ptid = tid ^ 32;
  f32x2 woPpk[4], woPXpk[4], woHpk[4];
#pragma unroll
  for (int B = 0; B < 4; ++B) {
    float sgn = ((tid >> B) & 1) ? -1.f : 1.f;
    float cO = cosf(thA[3 - B]) * sgn;    // own gate-type VQC1
    float cH = cosf(thr1[3 - B]) * sgn;   // VQC2
    float wo  = W_out[(3 - B) * HID + tid];
    float wo1 = W_out[(3 - B) * HID + tid + 64];
    float wp  = W_out[(3 - B) * HID + ptid];
    float wp1 = W_out[(3 - B) * HID + ptid + 64];
    f32x2 a, c, h;
    a.x = wo * cO;  a.y = wo1 * cO;
    c.x = wp * cO;  c.y = wp1 * cO;
    h.x = wo * cH;  h.y = wo1 * cH;
    woPpk[B] = a; woPXpk[B] = c; woHpk[B] = h;
  }
  const float L2E = 1.4426950408889634f;
  f32x2 nbcpk, bc2pk;
  nbcpk.x = -b_out[tid] * L2E;        nbcpk.y = -b_out[tid + 64] * L2E;
  bc2pk.x =  b_out[tid] * (2.f * L2E); bc2pk.y =  b_out[tid + 64] * (2.f * L2E);

  auto dot4pk = [](const float* e, const f32x2* w) -> f32x2 {
    f32x2 d = s2(e[0]) * w[0];
    d = s2(e[1]) * w[1] + d;
    d = s2(e[2]) * w[2] + d;
    d = s2(e[3]) * w[3] + d;
    return d;
  };

  f32x2 hpk; hpk.x = 0.f; hpk.y = 0.f;   // h[tid], h[tid+64]
  const float* pxw = xw + ((long)b * TSEQ + (dir ? TSEQ - 1 : 0)) * QDIM;
  const long xstep = dir ? -QDIM : QDIM;
  float xc = pxw[l4]; pxw += xstep;
  float xn = pxw[l4]; pxw += xstep;

  float* po  = out + (long)b * TSEQ * HID + tid;
  float* pbf = (float*)bwdws + (long)b * TSEQ * HID + tid;
  u16*   pbh = (u16*)bwdws + (long)b * TSEQ * HID + tid;

#pragma unroll 1
  for (int t = 0; t < TSEQ; ++t) {
    float xnn = pxw[l4]; pxw += xstep;   // prefetch t+2 (ws padded; overrun harmless)

    // ---- y = h @ W_h (permuted cols) + xwP ----
    f32x2 hh0 = s2(hpk.x);
    f32x2 hh1 = s2(hpk.y);
    float v[16];
#pragma unroll
    for (int i = 0; i < 8; ++i) {
      f32x2 a = hh0 * w0p[i] + hh1 * w1p[i];
      v[2 * i] = a.x; v[2 * i + 1] = a.y;
    }
    float yv = bfr(v) + xc;

    // ---- VQC1 collapsed: p[col] = yP[col]^2; cos(theta) folded into woP tables ----
    float prb = yv * yv;

    float n2, eb[4];
    ebf(prb, n2, eb);
    float inv = rcpf(n2);   // n2 == |y|^2, shared by both gate types
    float nic = inv * (-L2E);

    // dots: dO = own gate type / own cols; dXp = own gate type / partner cols;
    // one pls32 crossing delivers the other gate type's dots for our m-pair.
    f32x2 dO  = dot4pk(eb, woPpk);
    f32x2 dXp = dot4pk(eb, woPXpk);
    f32x2 recv;
    recv.x = pls32_other(dXp.x);
    recv.y = pls32_other(dXp.y);
    f32x2 rd, zd;
    rd.x = lt2 ? dO.x : recv.x;  rd.y = lt2 ? dO.y : recv.y;
    zd.x = lt2 ? recv.x : dO.x;  zd.y = lt2 ? recv.y : dO.y;

    f32x2 ra = rd * s2(nic) + nbcpk;
    f32x2 za = zd * s2(nic) + nbcpk;
    float r0 = rcpf(1.f + ex2(ra.x));
    float r1 = rcpf(1.f + ex2(ra.y));
    float z0 = rcpf(1.f + ex2(za.x));
    float z1 = rcpf(1.f + ex2(za.y));

    // ---- v1 = (r*h) @ W_h + xwP ----
    f32x2 rpk; rpk.x = r0; rpk.y = r1;
    f32x2 rh = rpk * hpk;
    hh0 = s2(rh.x);
    hh1 = s2(rh.y);
#pragma unroll
    for (int i = 0; i < 8; ++i) {
      f32x2 a = hh0 * w0p[i] + hh1 * w1p[i];
      v[2 * i] = a.x; v[2 * i + 1] = a.y;
    }
    float vv = bfr(v) + xc;

    // ---- VQC2 collapsed ----
    float prb2 = vv * vv;

    float n2b, eb2[4];
    ebf(prb2, n2b, eb2);
    float invb = rcpf(n2b);
    f32x2 hd = dot4pk(eb2, woHpk);
    f32x2 ha = hd * s2(invb * (2.f * L2E)) + bc2pk;
    float h20 = fmaf(-2.f, rcpf(1.f + ex2(ha.x)), 1.f);
    float h21 = fmaf(-2.f, rcpf(1.f + ex2(ha.y)), 1.f);

    f32x2 h2pk; h2pk.x = h20; h2pk.y = h21;
    f32x2 zpk;  zpk.x  = z0;  zpk.y  = z1;
    hpk = zpk * (h2pk - hpk) + hpk;

    f32x2 opk = hpk * s2(0.5f);
    if (dir == 0) {
      po[0]  = opk.x;
      po[64] = opk.y;
      po += HID;
    } else if (BF16WS) {
      pbh[0]  = f2bf(opk.x);
      pbh[64] = f2bf(opk.y);
      pbh += HID;
    } else {
      pbf[0]  = opk.x;
      pbf[64] = opk.y;
      pbf += HID;
    }

    xc = xn; xn = xnn;
  }
}

// ---------------- kernel 3: out += bwd trajectory ----------------

template<bool BF16WS>
__global__ __launch_bounds__(256) void combine_k(float* __restrict__ out,
                                                 const void* __restrict__ bwd, long n4) {
  long i = (long)blockIdx.x * 256 + threadIdx.x;
  const long stride = (long)gridDim.x * 256;
  for (; i < n4; i += stride) {
    float4 o = reinterpret_cast<float4*>(out)[i];
    float ax, ay, az, aw;
    if (BF16WS) {
      ushort4 u = reinterpret_cast<const ushort4*>(bwd)[i];
      ax = __uint_as_float((u32)u.x << 16);
      ay = __uint_as_float((u32)u.y << 16);
      az = __uint_as_float((u32)u.z << 16);
      aw = __uint_as_float((u32)u.w << 16);
    } else {
      float4 a = reinterpret_cast<const float4*>(bwd)[i];
      ax = a.x; ay = a.y; az = a.z; aw = a.w;
    }
    o.x += ax; o.y += ay; o.z += az; o.w += aw;
    reinterpret_cast<float4*>(out)[i] = o;
  }
}

// ---------------- launch ----------------

extern "C" void kernel_launch(void* const* d_in, const int* in_sizes, int n_in,
                              void* d_out, int out_size, void* d_ws, size_t ws_size,
                              hipStream_t stream) {
  const float* x     = (const float*)d_in[0];
  const float* W_in  = (const float*)d_in[1];
  const float* b_in  = (const float*)d_in[2];
  const float* W_out = (const float*)d_in[3];
  const float* b_out = (const float*)d_in[4];
  const float* thr_f  = (const float*)d_in[5];
  const float* thr1_f = (const float*)d_in[6];
  const float* thu_f  = (const float*)d_in[7];
  const float* thr_b  = (const float*)d_in[8];
  const float* thr1_b = (const float*)d_in[9];
  const float* thu_b  = (const float*)d_in[10];
  float* out = (float*)d_out;

  char* ws = (char*)d_ws;
  const size_t PAD = 4096;   // xw prefetch over/under-run guard
  const size_t xw_bytes = (size_t)NB * TSEQ * QDIM * sizeof(float);   // 8 MB
  float* xw = (float*)(ws + PAD);
  void* bwd = (void*)(ws + PAD + xw_bytes + PAD);
  const size_t need_f32 = 2 * PAD + xw_bytes + (size_t)NB * TSEQ * HID * sizeof(float);
  const bool f32ws = (ws_size >= need_f32);

  xw_kernel<<<(NB * TSEQ) / 16, 256, 0, stream>>>(x, W_in, b_in, xw);

  if (f32ws) {
    qbigru_main<false><<<256, 64, 0, stream>>>(W_in, W_out, b_out,
        thr_f, thr1_f, thu_f, thr_b, thr1_b, thu_b, xw, out, bwd);
  } else {
    qbigru_main<true><<<256, 64, 0, stream>>>(W_in, W_out, b_out,
        thr_f, thr1_f, thu_f, thr_b, thr1_b, thu_b, xw, out, bwd);
  }

  const long n4 = (long)NB * TSEQ * HID / 4;
  if (f32ws) combine_k<false><<<2048, 256, 0, stream>>>(out, bwd, n4);
  else       combine_k<true><<<2048, 256, 0, stream>>>(out, bwd, n4);
}

// Round 10
// 584.178 us; speedup vs baseline: 1.3828x; 1.0368x over previous
//
#include <hip/hip_runtime.h>
#include <hip/hip_bf16.h>

#define TSEQ 1024
#define NB   128
#define HID  128
#define QDIM 16

typedef unsigned int  u32;
typedef unsigned short u16;
typedef float f32x2 __attribute__((ext_vector_type(2)));

// ---------------- cross-lane helpers (wave64) ----------------

template<int CTRL>
__device__ __forceinline__ int dpp_i(int x) {
  return __builtin_amdgcn_update_dpp(0, x, CTRL, 0xF, 0xF, true);
}
template<int CTRL>
__device__ __forceinline__ float dpp_f(float x) {
  return __int_as_float(dpp_i<CTRL>(__float_as_int(x)));
}

#ifdef __has_builtin
#if __has_builtin(__builtin_amdgcn_permlane16_swap) && __has_builtin(__builtin_amdgcn_permlane32_swap)
#define HAS_PLS 1
#endif
#endif
#ifndef HAS_PLS
#define HAS_PLS 0
#endif

__device__ __forceinline__ float pls16_sum(float x) {
#if HAS_PLS
  auto r = __builtin_amdgcn_permlane16_swap(__float_as_uint(x), __float_as_uint(x), false, false);
  return __uint_as_float(r[0]) + __uint_as_float(r[1]);
#else
  return x + __shfl_xor(x, 16, 64);
#endif
}
__device__ __forceinline__ float pls32_sum(float x) {
#if HAS_PLS
  auto r = __builtin_amdgcn_permlane32_swap(__float_as_uint(x), __float_as_uint(x), false, false);
  return __uint_as_float(r[0]) + __uint_as_float(r[1]);
#else
  return x + __shfl_xor(x, 32, 64);
#endif
}

__device__ __forceinline__ float rcpf(float x) { return __builtin_amdgcn_rcpf(x); }

__device__ __forceinline__ float ex2(float x) {
#if defined(__has_builtin)
#if __has_builtin(__builtin_amdgcn_exp2f)
  return __builtin_amdgcn_exp2f(x);
#else
  return exp2f(x);
#endif
#else
  return exp2f(x);
#endif
}

__device__ __forceinline__ u16 f2bf(float f) {
  u32 u = __float_as_uint(f);
  u32 r = (u + 0x7FFFu + ((u >> 16) & 1u)) >> 16;
  return (u16)r;
}

__device__ __forceinline__ f32x2 s2(float x) { f32x2 r; r.x = x; r.y = x; return r; }

// CNOT-ladder index map g (verified in R1-R9).
__device__ __forceinline__ int gperm(int t) {
  int u = t;
#define APPLY(c, tt) u ^= (((u >> (3 - (c))) & 1) << (3 - (tt)));
  APPLY(3, 1) APPLY(2, 0) APPLY(1, 3) APPLY(0, 2)
  APPLY(3, 0) APPLY(2, 3) APPLY(1, 2) APPLY(0, 1)
#undef APPLY
  return u;
}

// ---------------- kernel 1: xwP[b,t,j] = x[b,t,:] @ W_x[:,g(j)] + b_in[g(j)] ----------------

__global__ __launch_bounds__(256) void xw_kernel(
    const float* __restrict__ x, const float* __restrict__ W_in,
    const float* __restrict__ b_in, float* __restrict__ xw) {
  __shared__ __align__(16) float xs[16][132];
  __shared__ float wl[2048];
  __shared__ float bl[16];
  const int tid = threadIdx.x;
  const long r0 = (long)blockIdx.x * 16;
#pragma unroll
  for (int i = 0; i < 8; ++i) {
    int idx = tid + i * 256;
    xs[idx >> 7][idx & 127] = x[(r0 + (idx >> 7)) * 128 + (idx & 127)];
  }
#pragma unroll
  for (int i = 0; i < 8; ++i) {
    int idx = tid + i * 256;
    wl[idx] = W_in[2048 + idx];   // W_x = W_in[128:256, :]
  }
  if (tid < 16) bl[tid] = b_in[tid];
  __syncthreads();
  const int rr = tid >> 4, j = tid & 15;
  const int gj = gperm(j);
  float s = bl[gj];
#pragma unroll
  for (int k4 = 0; k4 < 32; ++k4) {
    float4 v = *reinterpret_cast<const float4*>(&xs[rr][k4 * 4]);
    int kb = k4 * 4;
    s = fmaf(v.x, wl[(kb + 0) * 16 + gj], s);
    s = fmaf(v.y, wl[(kb + 1) * 16 + gj], s);
    s = fmaf(v.z, wl[(kb + 2) * 16 + gj], s);
    s = fmaf(v.w, wl[(kb + 3) * 16 + gj], s);
  }
  xw[(r0 + rr) * 16 + j] = s;
}

// ---------------- kernel 2: recurrence. 256 blocks x 1 wave; all-register ----------------
// Analytic VQC collapse (R9): p[s] = yP[s]^2 (theta-independent!);
// expval factor cos(theta_w) folded into constant tables. Since p no longer
// depends on the theta set, BOTH gate types are computed locally per lane:
//   rd = dot(eb, woRpk)  [cos(th_reset) folded]
//   zd = dot(eb, woZpk)  [cos(th_update) folded]
// -> no row split, no partner dots, no pls32 crossing, no cndmask select.

template<bool BF16WS>
__global__ __launch_bounds__(64)
__attribute__((amdgpu_waves_per_eu(1, 2)))
void qbigru_main(
    const float* __restrict__ W_in,
    const float* __restrict__ W_out,
    const float* __restrict__ b_out,
    const float* __restrict__ thr_f, const float* __restrict__ thr1_f, const float* __restrict__ thu_f,
    const float* __restrict__ thr_b, const float* __restrict__ thr1_b, const float* __restrict__ thu_b,
    const float* __restrict__ xw,
    float* __restrict__ out,
    void* __restrict__ bwdws) {
  const int tid = threadIdx.x;
  const int l4  = tid & 15;
  const int dir = blockIdx.x >> 7;
  const int b   = blockIdx.x & 127;

  // xor4-within-row via row_shl:4 / row_shr:4 + probe-derived select (convention-proof).
  const int pshl = dpp_i<0x104>(tid);
  const int sel4 = (pshl == (tid ^ 4)) ? ~0 : 0;
  auto xor4f = [&](float x) {
    int a = dpp_i<0x104>(__float_as_int(x));
    int c = dpp_i<0x114>(__float_as_int(x));
    return __int_as_float((a & sel4) | (c & ~sel4));
  };

  // Select-free reduce-scatter. Input: v[i] = partial of column (i ^ l4).
  // Output: full 64-lane sum for column l4, replicated in every lane.
  auto bfr = [&](const float* v) -> float {
    float w1[8];
#pragma unroll
    for (int j = 0; j < 8; ++j) w1[j] = v[2 * j] + dpp_f<0xB1>(v[2 * j + 1]);   // col bit0 (xor1)
    float w2[4];
#pragma unroll
    for (int j = 0; j < 4; ++j) w2[j] = w1[2 * j] + dpp_f<0x4E>(w1[2 * j + 1]); // col bit1 (xor2)
    float w3[2];
#pragma unroll
    for (int j = 0; j < 2; ++j) w3[j] = w2[j] + dpp_f<0x128>(w2[j + 2]);        // col bit3 (xor8)
    float y0 = w3[0] + xor4f(w3[1]);                                            // col bit2 (xor4)
    return pls32_sum(pls16_sum(y0));
  };

  // +/- butterfly: eb[B](l) = (-1)^{l_B} * sum_s p[s]*(1-2*bit_B(s)); n2 = sum p.
  auto ebf = [&](float p, float& n2, float* eb) {
    float s4 = xor4f(p);
    float P  = p + s4, M2 = p - s4;
    float dP = dpp_f<0x128>(P), dM2 = dpp_f<0x128>(M2);
    float P3 = P + dP, M3 = P - dP; M2 = M2 + dM2;
    float a1 = dpp_f<0x4E>(P3), a2 = dpp_f<0x4E>(M3), a3 = dpp_f<0x4E>(M2);
    float P1 = P3 + a1, M1 = P3 - a1; M3 += a2; M2 += a3;
    float b0_ = dpp_f<0xB1>(P1), b1_ = dpp_f<0xB1>(M1), b3_ = dpp_f<0xB1>(M3), b2_ = dpp_f<0xB1>(M2);
    n2 = P1 + b0_;
    eb[0] = P1 - b0_; eb[1] = M1 + b1_; eb[3] = M3 + b3_; eb[2] = M2 + b2_;
  };

  // ---- per-lane constants ----
  const float* thr  = dir ? thr_b  : thr_f;
  const float* thr1 = dir ? thr1_b : thr1_f;
  const float* thu  = dir ? thu_b  : thu_f;

  // W_h, XOR layout + CNOT perm folded: slot i holds column g(i ^ l4). Lane covers k = tid, tid+64.
  f32x2 w0p[8], w1p[8];
#pragma unroll
  for (int i = 0; i < 8; ++i) {
    int ja = gperm((2 * i) ^ l4), jb = gperm((2 * i + 1) ^ l4);
    f32x2 a, c;
    a.x = W_in[tid * QDIM + ja];        a.y = W_in[tid * QDIM + jb];
    c.x = W_in[(tid + 64) * QDIM + ja]; c.y = W_in[(tid + 64) * QDIM + jb];
    w0p[i] = a; w1p[i] = c;
  }

  // W_out pk pairs over (m=tid, m=tid+64), wire w = 3-B, with e-butterfly sign
  // (-1)^{l_B} and the analytic cos(theta_w) factor folded in.
  // woRpk: reset thetas; woZpk: update thetas; woHpk: VQC2 thetas.
  f32x2 woRpk[4], woZpk[4], woHpk[4];
#pragma unroll
  for (int B = 0; B < 4; ++B) {
    float sgn = ((tid >> B) & 1) ? -1.f : 1.f;
    float cR = cosf(thr[3 - B])  * sgn;
    float cZ = cosf(thu[3 - B])  * sgn;
    float cH = cosf(thr1[3 - B]) * sgn;
    float wo  = W_out[(3 - B) * HID + tid];
    float wo1 = W_out[(3 - B) * HID + tid + 64];
    f32x2 rr_, zz_, hh_;
    rr_.x = wo * cR;  rr_.y = wo1 * cR;
    zz_.x = wo * cZ;  zz_.y = wo1 * cZ;
    hh_.x = wo * cH;  hh_.y = wo1 * cH;
    woRpk[B] = rr_; woZpk[B] = zz_; woHpk[B] = hh_;
  }
  const float L2E = 1.4426950408889634f;
  f32x2 nbcpk, bc2pk;
  nbcpk.x = -b_out[tid] * L2E;        nbcpk.y = -b_out[tid + 64] * L2E;
  bc2pk.x =  b_out[tid] * (2.f * L2E); bc2pk.y =  b_out[tid + 64] * (2.f * L2E);

  auto dot4pk = [](const float* e, const f32x2* w) -> f32x2 {
    f32x2 d = s2(e[0]) * w[0];
    d = s2(e[1]) * w[1] + d;
    d = s2(e[2]) * w[2] + d;
    d = s2(e[3]) * w[3] + d;
    return d;
  };

  f32x2 hpk; hpk.x = 0.f; hpk.y = 0.f;   // h[tid], h[tid+64]
  const float* pxw = xw + ((long)b * TSEQ + (dir ? TSEQ - 1 : 0)) * QDIM;
  const long xstep = dir ? -QDIM : QDIM;
  float xc = pxw[l4]; pxw += xstep;
  float xn = pxw[l4]; pxw += xstep;

  float* po  = out + (long)b * TSEQ * HID + tid;
  float* pbf = (float*)bwdws + (long)b * TSEQ * HID + tid;
  u16*   pbh = (u16*)bwdws + (long)b * TSEQ * HID + tid;

#pragma unroll 1
  for (int t = 0; t < TSEQ; ++t) {
    float xnn = pxw[l4]; pxw += xstep;   // prefetch t+2 (ws padded; overrun harmless)

    // ---- y = h @ W_h (permuted cols) + xwP ----
    f32x2 hh0 = s2(hpk.x);
    f32x2 hh1 = s2(hpk.y);
    float v[16];
#pragma unroll
    for (int i = 0; i < 8; ++i) {
      f32x2 a = hh0 * w0p[i] + hh1 * w1p[i];
      v[2 * i] = a.x; v[2 * i + 1] = a.y;
    }
    float yv = bfr(v) + xc;

    // ---- VQC1 collapsed: p[col] = yP[col]^2 ----
    float prb = yv * yv;

    float n2, eb[4];
    ebf(prb, n2, eb);
    float inv = rcpf(n2);   // n2 == |y|^2, shared by both gate types
    float nic = inv * (-L2E);

    // both gate dots local (theta lives in the folded tables)
    f32x2 rd = dot4pk(eb, woRpk);
    f32x2 zd = dot4pk(eb, woZpk);

    f32x2 ra = rd * s2(nic) + nbcpk;
    f32x2 za = zd * s2(nic) + nbcpk;
    float r0 = rcpf(1.f + ex2(ra.x));
    float r1 = rcpf(1.f + ex2(ra.y));
    float z0 = rcpf(1.f + ex2(za.x));
    float z1 = rcpf(1.f + ex2(za.y));

    // ---- v1 = (r*h) @ W_h + xwP ----
    f32x2 rpk; rpk.x = r0; rpk.y = r1;
    f32x2 rh = rpk * hpk;
    hh0 = s2(rh.x);
    hh1 = s2(rh.y);
#pragma unroll
    for (int i = 0; i < 8; ++i) {
      f32x2 a = hh0 * w0p[i] + hh1 * w1p[i];
      v[2 * i] = a.x; v[2 * i + 1] = a.y;
    }
    float vv = bfr(v) + xc;

    // ---- VQC2 collapsed ----
    float prb2 = vv * vv;

    float n2b, eb2[4];
    ebf(prb2, n2b, eb2);
    float invb = rcpf(n2b);
    f32x2 hd = dot4pk(eb2, woHpk);
    f32x2 ha = hd * s2(invb * (2.f * L2E)) + bc2pk;
    float h20 = fmaf(-2.f, rcpf(1.f + ex2(ha.x)), 1.f);
    float h21 = fmaf(-2.f, rcpf(1.f + ex2(ha.y)), 1.f);

    f32x2 h2pk; h2pk.x = h20; h2pk.y = h21;
    f32x2 zpk;  zpk.x  = z0;  zpk.y  = z1;
    hpk = zpk * (h2pk - hpk) + hpk;

    f32x2 opk = hpk * s2(0.5f);
    if (dir == 0) {
      po[0]  = opk.x;
      po[64] = opk.y;
      po += HID;
    } else if (BF16WS) {
      pbh[0]  = f2bf(opk.x);
      pbh[64] = f2bf(opk.y);
      pbh += HID;
    } else {
      pbf[0]  = opk.x;
      pbf[64] = opk.y;
      pbf += HID;
    }

    xc = xn; xn = xnn;
  }
}

// ---------------- kernel 3: out += bwd trajectory ----------------

template<bool BF16WS>
__global__ __launch_bounds__(256) void combine_k(float* __restrict__ out,
                                                 const void* __restrict__ bwd, long n4) {
  long i = (long)blockIdx.x * 256 + threadIdx.x;
  const long stride = (long)gridDim.x * 256;
  for (; i < n4; i += stride) {
    float4 o = reinterpret_cast<float4*>(out)[i];
    float ax, ay, az, aw;
    if (BF16WS) {
      ushort4 u = reinterpret_cast<const ushort4*>(bwd)[i];
      ax = __uint_as_float((u32)u.x << 16);
      ay = __uint_as_float((u32)u.y << 16);
      az = __uint_as_float((u32)u.z << 16);
      aw = __uint_as_float((u32)u.w << 16);
    } else {
      float4 a = reinterpret_cast<const float4*>(bwd)[i];
      ax = a.x; ay = a.y; az = a.z; aw = a.w;
    }
    o.x += ax; o.y += ay; o.z += az; o.w += aw;
    reinterpret_cast<float4*>(out)[i] = o;
  }
}

// ---------------- launch ----------------

extern "C" void kernel_launch(void* const* d_in, const int* in_sizes, int n_in,
                              void* d_out, int out_size, void* d_ws, size_t ws_size,
                              hipStream_t stream) {
  const float* x     = (const float*)d_in[0];
  const float* W_in  = (const float*)d_in[1];
  const float* b_in  = (const float*)d_in[2];
  const float* W_out = (const float*)d_in[3];
  const float* b_out = (const float*)d_in[4];
  const float* thr_f  = (const float*)d_in[5];
  const float* thr1_f = (const float*)d_in[6];
  const float* thu_f  = (const float*)d_in[7];
  const float* thr_b  = (const float*)d_in[8];
  const float* thr1_b = (const float*)d_in[9];
  const float* thu_b  = (const float*)d_in[10];
  float* out = (float*)d_out;

  char* ws = (char*)d_ws;
  const size_t PAD = 4096;   // xw prefetch over/under-run guard
  const size_t xw_bytes = (size_t)NB * TSEQ * QDIM * sizeof(float);   // 8 MB
  float* xw = (float*)(ws + PAD);
  void* bwd = (void*)(ws + PAD + xw_bytes + PAD);
  const size_t need_f32 = 2 * PAD + xw_bytes + (size_t)NB * TSEQ * HID * sizeof(float);
  const bool f32ws = (ws_size >= need_f32);

  xw_kernel<<<(NB * TSEQ) / 16, 256, 0, stream>>>(x, W_in, b_in, xw);

  if (f32ws) {
    qbigru_main<false><<<256, 64, 0, stream>>>(W_in, W_out, b_out,
        thr_f, thr1_f, thu_f, thr_b, thr1_b, thu_b, xw, out, bwd);
  } else {
    qbigru_main<true><<<256, 64, 0, stream>>>(W_in, W_out, b_out,
        thr_f, thr1_f, thu_f, thr_b, thr1_b, thu_b, xw, out, bwd);
  }

  const long n4 = (long)NB * TSEQ * HID / 4;
  if (f32ws) combine_k<false><<<2048, 256, 0, stream>>>(out, bwd, n4);
  else       combine_k<true><<<2048, 256, 0, stream>>>(out, bwd, n4);
}